// Round 7
// baseline (99.389 us; speedup 1.0000x reference)
//
#include <hip/hip_runtime.h>

// Mamba-2 SSD forward. B=2, L=4096, H=16, P=S=64, chunk=64, n=64 chunks.
// ssd_m:   LDS-free, barrier-free. M = L∘(C·B^T) via direct global frag loads,
//          frag-native bf16 store to Mws. Per-wave shfl cumsum of A.
// ssd_h:   h_final^T = (dte∘X)^T weighted by B, minimal LDS transpose (X^T,B^T),
//          one barrier, frag-native bf16 store to hws. Writes chunk log-decay.
// ssd_scan: element-wise inter-chunk scan on frag-native hws (coalesced, pipelined).
// ssd_y:   LDS-free, barrier-free. Y^T = X^T·M^T + E_i∘(h^T·C^T); C read directly,
//          decay-from-start applied in fp32 epilogue.

#define BSZ 2
#define LSEQ 4096
#define NH 16
#define NC 64
#define NCH (BSZ * NH * NC)      // 2048 chunk tasks
#define SCAN_G 8
#define CHW 4096                 // ushort elems per chunk ws tile
#define TILE_USHORTS ((size_t)NCH * CHW)

typedef float f32x4 __attribute__((ext_vector_type(4)));
typedef __bf16 bf16x8 __attribute__((ext_vector_type(8)));

union FragU { uint4 u; bf16x8 b; unsigned short s[8]; };

__device__ __forceinline__ unsigned short f2b(float x) {
    union { float f; unsigned u; } c; c.f = x;
    unsigned r = c.u + 0x7fffu + ((c.u >> 16) & 1u);   // RNE bf16
    return (unsigned short)(r >> 16);
}
__device__ __forceinline__ float b2f(unsigned short v) {
    union { unsigned u; float f; } c; c.u = ((unsigned)v) << 16;
    return c.f;
}

// LDS element-index swizzle (transposed tiles), 64 ushort per row
__device__ __forceinline__ int tr_e(int row, int k) { return row * 64 + (k ^ (((row >> 1) & 7) << 3)); }

__device__ __forceinline__ bf16x8 frag_tr(const unsigned short* buf, int tile, int kk, int l) {
    FragU f; f.u = *(const uint4*)&buf[tr_e(tile * 16 + (l & 15), kk * 32 + ((l >> 4) << 3))];
    return f.b;
}

// pack two float4 (8 consecutive fp32) into a bf16x8 fragment
__device__ __forceinline__ bf16x8 pack8(const float4 a, const float4 b) {
    FragU f;
    f.s[0] = f2b(a.x); f.s[1] = f2b(a.y); f.s[2] = f2b(a.z); f.s[3] = f2b(a.w);
    f.s[4] = f2b(b.x); f.s[5] = f2b(b.y); f.s[6] = f2b(b.z); f.s[7] = f2b(b.w);
    return f.b;
}

// per-wave inclusive cumsum of A over the chunk (lane l holds Acs[l])
__device__ __forceinline__ float wave_cumsum_A(const float* Ag, int row0, int h, int l) {
    float a = Ag[(unsigned)(row0 + l) * NH + h];
    #pragma unroll
    for (int off = 1; off < 64; off <<= 1) {
        float v = __shfl_up(a, off, 64);
        if (l >= off) a += v;
    }
    return a;
}

// ---------------- ssd_m: M = L∘(C·B^T), LDS-free ----------------
__global__ __launch_bounds__(256) void ssd_m(
    const float* __restrict__ Ag, const float* __restrict__ Bg,
    const float* __restrict__ Cg, unsigned short* __restrict__ Mws)
{
    const int tid = threadIdx.x;
    const int l = tid & 63;
    const int w = tid >> 6;
    const int n = blockIdx.x & (NC - 1);
    const int h = (blockIdx.x >> 6) & (NH - 1);
    const int b = blockIdx.x >> 10;
    const int row0 = b * LSEQ + n * 64;
    const unsigned chb = (unsigned)blockIdx.x * CHW;
    const int i15 = l & 15;
    const int s0base = (l >> 4) << 3;

    const float acs = wave_cumsum_A(Ag, row0, h, l);

    // A-frag: B row j, k=s contiguous (direct global)
    const int j = w * 16 + i15;
    bf16x8 aB[2];
    #pragma unroll
    for (int kk = 0; kk < 2; ++kk) {
        const unsigned g = ((unsigned)(row0 + j) * NH + h) * 64 + kk * 32 + s0base;
        aB[kk] = pack8(*(const float4*)&Bg[g], *(const float4*)&Bg[g + 4]);
    }

    // B-frags: C rows i, k=s contiguous; mm: D[j][i] = sum_s B[j][s] C[i][s]
    const f32x4 zero = {0.f, 0.f, 0.f, 0.f};
    f32x4 accT[4] = {zero, zero, zero, zero};
    #pragma unroll
    for (int kk = 0; kk < 2; ++kk) {
        #pragma unroll
        for (int ti = 0; ti < 4; ++ti) {
            const int i = ti * 16 + i15;
            const unsigned g = ((unsigned)(row0 + i) * NH + h) * 64 + kk * 32 + s0base;
            const bf16x8 bC = pack8(*(const float4*)&Cg[g], *(const float4*)&Cg[g + 4]);
            accT[ti] = __builtin_amdgcn_mfma_f32_16x16x32_bf16(aB[kk], bC, accT[ti], 0, 0, 0);
        }
    }

    // epilogue: M[i][j] = (i>=j) ? exp(acs_i - acs_j) * CB[i][j] : 0
    const int il = (l >> 4) << 2;
    const int j0 = w * 16 + il;
    float Rj[4];
    #pragma unroll
    for (int r = 0; r < 4; ++r) Rj[r] = __expf(-__shfl(acs, j0 + r, 64));
    #pragma unroll
    for (int ti = 0; ti < 4; ++ti) {
        const int i = ti * 16 + i15;
        const float Ei = __expf(__shfl(acs, i, 64));
        ushort4 m;
        m.x = (i >= j0 + 0) ? f2b(Ei * Rj[0] * accT[ti][0]) : (unsigned short)0;
        m.y = (i >= j0 + 1) ? f2b(Ei * Rj[1] * accT[ti][1]) : (unsigned short)0;
        m.z = (i >= j0 + 2) ? f2b(Ei * Rj[2] * accT[ti][2]) : (unsigned short)0;
        m.w = (i >= j0 + 3) ? f2b(Ei * Rj[3] * accT[ti][3]) : (unsigned short)0;
        *(ushort4*)&Mws[chb + (((ti * 4 + w) * 64 + l) << 2)] = m;
    }
}

// ---------------- ssd_h: h_final^T, minimal LDS ----------------
__global__ __launch_bounds__(256) void ssd_h(
    const float* __restrict__ Xg, const float* __restrict__ Ag,
    const float* __restrict__ Bg, unsigned short* __restrict__ hws,
    float* __restrict__ dws)
{
    __shared__ __align__(16) unsigned short sBt[64 * 64];  // B^T [s][c]
    __shared__ __align__(16) unsigned short sXt[64 * 64];  // (dte∘X)^T [p][c]

    const int tid = threadIdx.x;
    const int l = tid & 63;
    const int w = tid >> 6;
    const int n = blockIdx.x & (NC - 1);
    const int h = (blockIdx.x >> 6) & (NH - 1);
    const int b = blockIdx.x >> 10;
    const int row0 = b * LSEQ + n * 64;
    const unsigned chb = (unsigned)blockIdx.x * CHW;
    const int p0 = (tid & 15) * 4;

    // issue X/B loads early
    float4 xv[4], bv[4];
    #pragma unroll
    for (int it = 0; it < 4; ++it) {
        const int c = (tid >> 4) + it * 16;
        const unsigned g = ((unsigned)(row0 + c) * NH + h) * 64 + p0;
        xv[it] = *(const float4*)&Xg[g];
        bv[it] = *(const float4*)&Bg[g];
    }

    const float acs = wave_cumsum_A(Ag, row0, h, l);
    const float a63 = __shfl(acs, 63, 64);
    if (tid == 63) dws[blockIdx.x] = a63;   // log chunk decay

    // stage transposed bf16 tiles; dte via per-wave shfl (no barrier needed pre-staging)
    #pragma unroll
    for (int it = 0; it < 4; ++it) {
        const int c = (tid >> 4) + it * 16;
        const float dte = __expf(a63 - __shfl(acs, c & 63, 64));
        sBt[tr_e(p0 + 0, c)] = f2b(bv[it].x);
        sBt[tr_e(p0 + 1, c)] = f2b(bv[it].y);
        sBt[tr_e(p0 + 2, c)] = f2b(bv[it].z);
        sBt[tr_e(p0 + 3, c)] = f2b(bv[it].w);
        sXt[tr_e(p0 + 0, c)] = f2b(xv[it].x * dte);
        sXt[tr_e(p0 + 1, c)] = f2b(xv[it].y * dte);
        sXt[tr_e(p0 + 2, c)] = f2b(xv[it].z * dte);
        sXt[tr_e(p0 + 3, c)] = f2b(xv[it].w * dte);
    }
    __syncthreads();

    // D[s][p] = sum_c B[c][s] (dte∘X)[c][p]; wave w owns s in [16w,16w+16)
    const f32x4 zero = {0.f, 0.f, 0.f, 0.f};
    f32x4 accH[4] = {zero, zero, zero, zero};
    #pragma unroll
    for (int kk = 0; kk < 2; ++kk) {
        const bf16x8 aBt = frag_tr(sBt, w, kk, l);
        #pragma unroll
        for (int tp = 0; tp < 4; ++tp)
            accH[tp] = __builtin_amdgcn_mfma_f32_16x16x32_bf16(aBt, frag_tr(sXt, tp, kk, l), accH[tp], 0, 0, 0);
    }

    // h store, fragment-native: elem (p=tp*16+(l&15), s=w*16+il+r)
    const int il = (l >> 4) << 2;
    const int kk = w >> 1;
    const int q3 = ((w & 1) << 1) | (il >> 3);
    const int e0 = il & 7;
    const int lt = q3 * 16 + (l & 15);
    #pragma unroll
    for (int tp = 0; tp < 4; ++tp) {
        ushort4 o;
        o.x = f2b(accH[tp][0]); o.y = f2b(accH[tp][1]);
        o.z = f2b(accH[tp][2]); o.w = f2b(accH[tp][3]);
        *(ushort4*)&hws[chb + (((kk * 4 + tp) * 64 + lt) << 3) + e0] = o;
    }
}

// ---------------- scan: element-wise over chunks (in-place, coalesced) ----------------
__global__ __launch_bounds__(256) void ssd_scan(unsigned short* __restrict__ hws,
                                                const float* __restrict__ dws)
{
    __shared__ float sD[NC];
    const int tid = threadIdx.x;
    const int bh = blockIdx.x / SCAN_G;
    const int g = blockIdx.x % SCAN_G;
    if (tid < NC) sD[tid] = __expf(dws[bh * NC + tid]);   // chunk decay from log
    __syncthreads();

    unsigned* hw32 = (unsigned*)hws;
    const unsigned base = (unsigned)bh * NC * 2048u + g * 256u + tid;

    unsigned buf[4];
    #pragma unroll
    for (int j = 0; j < 4; ++j) buf[j] = hw32[base + j * 2048u];

    float cx = 0.f, cy = 0.f;
    #pragma unroll 4
    for (int c = 0; c < NC; ++c) {
        const unsigned cur = buf[c & 3];
        if (c + 4 < NC) buf[c & 3] = hw32[base + (unsigned)(c + 4) * 2048u];
        hw32[base + (unsigned)c * 2048u] = (unsigned)f2b(cx) | ((unsigned)f2b(cy) << 16);
        const float d = sD[c];
        cx = d * cx + b2f((unsigned short)(cur & 0xffffu));
        cy = d * cy + b2f((unsigned short)(cur >> 16));
    }
}

// ---------------- ssd_y: LDS-free, barrier-free ----------------
// Y[i][p] = sum_j M[i][j] X[j][p] + E_i * sum_s C[i][s] h_inter[s][p]
__global__ __launch_bounds__(256) void ssd_y(
    const float* __restrict__ Xg, const float* __restrict__ Ag,
    const float* __restrict__ Cg, const unsigned short* __restrict__ Mws,
    const unsigned short* __restrict__ hws, float* __restrict__ Yg)
{
    const int tid = threadIdx.x;
    const int l = tid & 63;
    const int w = tid >> 6;
    const int n = blockIdx.x & (NC - 1);
    const int h = (blockIdx.x >> 6) & (NH - 1);
    const int b = blockIdx.x >> 10;
    const int row0 = b * LSEQ + n * 64;
    const unsigned chb = (unsigned)blockIdx.x * CHW;
    const int i15 = l & 15;
    const int p = w * 16 + i15;
    const int s0base = (l >> 4) << 3;

    const float acs = wave_cumsum_A(Ag, row0, h, l);

    // A-frags: X^T (scalar fp32 loads, lanes coalesce) and h^T (uint4 frag-native)
    bf16x8 aX[2], aH[2];
    #pragma unroll
    for (int kk = 0; kk < 2; ++kk) {
        const int c0 = kk * 32 + s0base;
        bf16x8 x;
        #pragma unroll
        for (int e = 0; e < 8; ++e)
            x[e] = (__bf16)Xg[((unsigned)(row0 + c0 + e) * NH + h) * 64 + p];
        aX[kk] = x;
        FragU f; f.u = *(const uint4*)&hws[chb + (((kk * 4 + w) * 64 + l) << 3)];
        aH[kk] = f.b;
    }

    const f32x4 zero = {0.f, 0.f, 0.f, 0.f};
    f32x4 accY[4] = {zero, zero, zero, zero};
    f32x4 accI[4] = {zero, zero, zero, zero};
    #pragma unroll
    for (int kk = 0; kk < 2; ++kk) {
        const int j0 = kk * 32 + s0base;
        const int wj = j0 >> 4;
        const int q = (j0 >> 2) & 3;
        #pragma unroll
        for (int ti = 0; ti < 4; ++ti) {
            // M B-frag from frag-native ws
            FragU mf;
            *(ushort4*)&mf.s[0] = *(const ushort4*)&Mws[chb + (((ti * 4 + wj) * 64 + q * 16 + i15) << 2)];
            *(ushort4*)&mf.s[4] = *(const ushort4*)&Mws[chb + (((ti * 4 + wj) * 64 + (q + 1) * 16 + i15) << 2)];
            // C B-frag direct from global (row i, k=s contiguous)
            const int i = ti * 16 + i15;
            const unsigned g = ((unsigned)(row0 + i) * NH + h) * 64 + kk * 32 + s0base;
            const bf16x8 cf = pack8(*(const float4*)&Cg[g], *(const float4*)&Cg[g + 4]);
            accY[ti] = __builtin_amdgcn_mfma_f32_16x16x32_bf16(aX[kk], mf.b, accY[ti], 0, 0, 0);
            accI[ti] = __builtin_amdgcn_mfma_f32_16x16x32_bf16(aH[kk], cf, accI[ti], 0, 0, 0);
        }
    }

    const int pbase = w * 16 + ((l >> 4) << 2);
    #pragma unroll
    for (int ti = 0; ti < 4; ++ti) {
        const int i = ti * 16 + i15;
        const float Ei = __expf(__shfl(acs, i, 64));   // decay_from_start, fp32-exact
        float4 o;
        o.x = accY[ti][0] + Ei * accI[ti][0];
        o.y = accY[ti][1] + Ei * accI[ti][1];
        o.z = accY[ti][2] + Ei * accI[ti][2];
        o.w = accY[ti][3] + Ei * accI[ti][3];
        *(float4*)&Yg[((unsigned)(row0 + i) * NH + h) * 64 + pbase] = o;
    }
}

extern "C" void kernel_launch(void* const* d_in, const int* in_sizes, int n_in,
                              void* d_out, int out_size, void* d_ws, size_t ws_size,
                              hipStream_t stream) {
    const float* X = (const float*)d_in[0];
    const float* A = (const float*)d_in[1];
    const float* Bm = (const float*)d_in[2];
    const float* Cm = (const float*)d_in[3];
    float* Y = (float*)d_out;
    unsigned short* hws = (unsigned short*)d_ws;        // 16.8 MB
    unsigned short* Mws = hws + TILE_USHORTS;           // 16.8 MB
    float* dws = (float*)(Mws + TILE_USHORTS);          // 8 KB (log chunk decays)

    ssd_m<<<NCH, 256, 0, stream>>>(A, Bm, Cm, Mws);
    ssd_h<<<NCH, 256, 0, stream>>>(X, A, Bm, hws, dws);
    ssd_scan<<<BSZ * NH * SCAN_G, 256, 0, stream>>>(hws, dws);
    ssd_y<<<NCH, 256, 0, stream>>>(X, A, Cm, Mws, hws, Y);
}

// Round 8
// 82.455 us; speedup vs baseline: 1.2054x; 1.2054x over previous
//
#include <hip/hip_runtime.h>

// Mamba-2 SSD forward. B=2, L=4096, H=16, P=S=64, chunk=64, n=64 chunks.
// K1 (ssd_k1): fused per-chunk frontend, one barrier:
//   mm1: CB = C·B^T with DIRECT global fragment loads (row-contiguous);
//        Cs = E∘C produced from the same C registers, contiguous frag-native store;
//        M  = L∘CB, contiguous frag-native store.
//   mmH: h_final from LDS-transposed X^T/B^T (the only LDS use).
// K2 (ssd_scan): element-wise inter-chunk scan on frag-native hws (4-deep pipeline).
// K3 (ssd_k3): unchanged from R6 (proven ~12us): LDS-free, barrier-free.

#define BSZ 2
#define LSEQ 4096
#define NH 16
#define NC 64
#define NCH (BSZ * NH * NC)      // 2048 chunk tasks
#define SCAN_G 8
#define CHW 4096                 // ushort elems per chunk ws tile
#define TILE_USHORTS ((size_t)NCH * CHW)

typedef float f32x4 __attribute__((ext_vector_type(4)));
typedef __bf16 bf16x8 __attribute__((ext_vector_type(8)));

union FragU { uint4 u; bf16x8 b; unsigned short s[8]; };

__device__ __forceinline__ unsigned short f2b(float x) {
    union { float f; unsigned u; } c; c.f = x;
    unsigned r = c.u + 0x7fffu + ((c.u >> 16) & 1u);   // RNE bf16
    return (unsigned short)(r >> 16);
}
__device__ __forceinline__ float b2f(unsigned short v) {
    union { unsigned u; float f; } c; c.u = ((unsigned)v) << 16;
    return c.f;
}

// LDS element-index swizzle (transposed tiles), 64 ushort per row
__device__ __forceinline__ int tr_e(int row, int k) { return row * 64 + (k ^ (((row >> 1) & 7) << 3)); }

__device__ __forceinline__ bf16x8 frag_tr(const unsigned short* buf, int tile, int kk, int l) {
    FragU f; f.u = *(const uint4*)&buf[tr_e(tile * 16 + (l & 15), kk * 32 + ((l >> 4) << 3))];
    return f.b;
}

__device__ __forceinline__ bf16x8 pack8(const float4 a, const float4 b) {
    FragU f;
    f.s[0] = f2b(a.x); f.s[1] = f2b(a.y); f.s[2] = f2b(a.z); f.s[3] = f2b(a.w);
    f.s[4] = f2b(b.x); f.s[5] = f2b(b.y); f.s[6] = f2b(b.z); f.s[7] = f2b(b.w);
    return f.b;
}
__device__ __forceinline__ bf16x8 pack8s(const float4 a, const float4 b, float sc) {
    FragU f;
    f.s[0] = f2b(a.x * sc); f.s[1] = f2b(a.y * sc); f.s[2] = f2b(a.z * sc); f.s[3] = f2b(a.w * sc);
    f.s[4] = f2b(b.x * sc); f.s[5] = f2b(b.y * sc); f.s[6] = f2b(b.z * sc); f.s[7] = f2b(b.w * sc);
    return f.b;
}

// ---------------- K1: fused frontend ----------------
__global__ __launch_bounds__(256) void ssd_k1(
    const float* __restrict__ Xg, const float* __restrict__ Ag,
    const float* __restrict__ Bg, const float* __restrict__ Cg,
    unsigned short* __restrict__ hws, unsigned short* __restrict__ Mws,
    unsigned short* __restrict__ Csws, float* __restrict__ dws)
{
    __shared__ __align__(16) unsigned short sBt[64 * 64];  // B^T [s][c]
    __shared__ __align__(16) unsigned short sXt[64 * 64];  // (dte∘X)^T [p][c]

    const int tid = threadIdx.x;
    const int l = tid & 63;
    const int w = tid >> 6;
    const int n = blockIdx.x & (NC - 1);
    const int h = (blockIdx.x >> 6) & (NH - 1);
    const int b = blockIdx.x >> 10;
    const int row0 = b * LSEQ + n * 64;
    const unsigned chb = (unsigned)blockIdx.x * CHW;
    const int i15 = l & 15;
    const int s0base = (l >> 4) << 3;
    const int p0 = (tid & 15) * 4;

    // --- issue the long-latency loads first ---
    float aRaw = Ag[(unsigned)(row0 + l) * NH + h];
    float4 xv[4], bv[4];
    #pragma unroll
    for (int it = 0; it < 4; ++it) {
        const int c = (tid >> 4) + it * 16;
        const unsigned g = ((unsigned)(row0 + c) * NH + h) * 64 + p0;
        xv[it] = *(const float4*)&Xg[g];
        bv[it] = *(const float4*)&Bg[g];
    }
    // A-frag rows of B for mm1 (direct global, row-contiguous)
    const int j = w * 16 + i15;
    bf16x8 aB[2];
    #pragma unroll
    for (int kk = 0; kk < 2; ++kk) {
        const unsigned g = ((unsigned)(row0 + j) * NH + h) * 64 + kk * 32 + s0base;
        aB[kk] = pack8(*(const float4*)&Bg[g], *(const float4*)&Bg[g + 4]);
    }

    // --- per-wave inclusive cumsum of A ---
    float acs = aRaw;
    #pragma unroll
    for (int off = 1; off < 64; off <<= 1) {
        float v = __shfl_up(acs, off, 64);
        if (l >= off) acs += v;
    }
    const float a63 = __shfl(acs, 63, 64);
    if (tid == 63) dws[blockIdx.x] = a63;   // log chunk decay

    // decay factors this thread needs
    float Ei4[4];
    #pragma unroll
    for (int ti = 0; ti < 4; ++ti) Ei4[ti] = __expf(__shfl(acs, ti * 16 + i15, 64));
    const int il = (l >> 4) << 2;
    const int j0 = w * 16 + il;
    float Rj[4];
    #pragma unroll
    for (int r = 0; r < 4; ++r) Rj[r] = __expf(-__shfl(acs, j0 + r, 64));

    // --- stage transposed LDS tiles (the only LDS use) ---
    #pragma unroll
    for (int it = 0; it < 4; ++it) {
        const int c = (tid >> 4) + it * 16;
        const float dte = __expf(a63 - __shfl(acs, c, 64));
        sBt[tr_e(p0 + 0, c)] = f2b(bv[it].x);
        sBt[tr_e(p0 + 1, c)] = f2b(bv[it].y);
        sBt[tr_e(p0 + 2, c)] = f2b(bv[it].z);
        sBt[tr_e(p0 + 3, c)] = f2b(bv[it].w);
        sXt[tr_e(p0 + 0, c)] = f2b(xv[it].x * dte);
        sXt[tr_e(p0 + 1, c)] = f2b(xv[it].y * dte);
        sXt[tr_e(p0 + 2, c)] = f2b(xv[it].z * dte);
        sXt[tr_e(p0 + 3, c)] = f2b(xv[it].w * dte);
    }

    // --- mm1: D[j][i] = sum_s B[j][s] C[i][s]; Cs = Ei∘C stored from the same regs ---
    const f32x4 zero = {0.f, 0.f, 0.f, 0.f};
    f32x4 accT[4] = {zero, zero, zero, zero};
    #pragma unroll
    for (int kk = 0; kk < 2; ++kk) {
        #pragma unroll
        for (int ti = 0; ti < 4; ++ti) {
            const int i = ti * 16 + i15;
            const unsigned g = ((unsigned)(row0 + i) * NH + h) * 64 + kk * 32 + s0base;
            const float4 c0 = *(const float4*)&Cg[g];
            const float4 c1 = *(const float4*)&Cg[g + 4];
            const bf16x8 bC = pack8(c0, c1);
            accT[ti] = __builtin_amdgcn_mfma_f32_16x16x32_bf16(aB[kk], bC, accT[ti], 0, 0, 0);
            FragU cs; cs.b = pack8s(c0, c1, Ei4[ti]);
            *(uint4*)&Csws[chb + (((kk * 4 + ti) * 64 + l) << 3)] = cs.u;   // contiguous
        }
    }

    // --- M epilogue: M[i][j] = (i>=j) ? Ei*Rj*CB : 0, frag-native contiguous store ---
    #pragma unroll
    for (int ti = 0; ti < 4; ++ti) {
        const int i = ti * 16 + i15;
        const float Ei = Ei4[ti];
        ushort4 m;
        m.x = (i >= j0 + 0) ? f2b(Ei * Rj[0] * accT[ti][0]) : (unsigned short)0;
        m.y = (i >= j0 + 1) ? f2b(Ei * Rj[1] * accT[ti][1]) : (unsigned short)0;
        m.z = (i >= j0 + 2) ? f2b(Ei * Rj[2] * accT[ti][2]) : (unsigned short)0;
        m.w = (i >= j0 + 3) ? f2b(Ei * Rj[3] * accT[ti][3]) : (unsigned short)0;
        *(ushort4*)&Mws[chb + (((ti * 4 + w) * 64 + l) << 2)] = m;
    }

    __syncthreads();

    // --- mmH: D[s][p] = sum_c B[c][s] (dte∘X)[c][p] ---
    f32x4 accH[4] = {zero, zero, zero, zero};
    #pragma unroll
    for (int kk = 0; kk < 2; ++kk) {
        const bf16x8 aBt = frag_tr(sBt, w, kk, l);
        #pragma unroll
        for (int tp = 0; tp < 4; ++tp)
            accH[tp] = __builtin_amdgcn_mfma_f32_16x16x32_bf16(aBt, frag_tr(sXt, tp, kk, l), accH[tp], 0, 0, 0);
    }

    // h store, fragment-native: elem (p=tp*16+(l&15), s=w*16+il+r)
    const int kk2 = w >> 1;
    const int q3 = ((w & 1) << 1) | (il >> 3);
    const int e0 = il & 7;
    const int lt = q3 * 16 + i15;
    #pragma unroll
    for (int tp = 0; tp < 4; ++tp) {
        ushort4 o;
        o.x = f2b(accH[tp][0]); o.y = f2b(accH[tp][1]);
        o.z = f2b(accH[tp][2]); o.w = f2b(accH[tp][3]);
        *(ushort4*)&hws[chb + (((kk2 * 4 + tp) * 64 + lt) << 3) + e0] = o;
    }
}

// ---------------- K2: element-wise scan over chunks (in-place, coalesced) ----------------
__global__ __launch_bounds__(256) void ssd_scan(unsigned short* __restrict__ hws,
                                                const float* __restrict__ dws)
{
    __shared__ float sD[NC];
    const int tid = threadIdx.x;
    const int bh = blockIdx.x / SCAN_G;
    const int g = blockIdx.x % SCAN_G;
    if (tid < NC) sD[tid] = __expf(dws[bh * NC + tid]);   // chunk decay from log
    __syncthreads();

    unsigned* hw32 = (unsigned*)hws;
    const unsigned base = (unsigned)bh * NC * 2048u + g * 256u + tid;

    unsigned buf[4];
    #pragma unroll
    for (int jj = 0; jj < 4; ++jj) buf[jj] = hw32[base + jj * 2048u];

    float cx = 0.f, cy = 0.f;
    #pragma unroll 4
    for (int c = 0; c < NC; ++c) {
        const unsigned cur = buf[c & 3];
        if (c + 4 < NC) buf[c & 3] = hw32[base + (unsigned)(c + 4) * 2048u];
        hw32[base + (unsigned)c * 2048u] = (unsigned)f2b(cx) | ((unsigned)f2b(cy) << 16);
        const float d = sD[c];
        cx = d * cx + b2f((unsigned short)(cur & 0xffffu));
        cy = d * cy + b2f((unsigned short)(cur >> 16));
    }
}

// ---------------- K3: LDS-free, barrier-free (unchanged from R6) ----------------
__global__ __launch_bounds__(256) void ssd_k3(
    const float* __restrict__ Xg, const unsigned short* __restrict__ Mws,
    const unsigned short* __restrict__ Csws, const unsigned short* __restrict__ hws,
    float* __restrict__ Yg)
{
    const int tid = threadIdx.x;
    const int l = tid & 63;
    const int w = tid >> 6;
    const int n = blockIdx.x & (NC - 1);
    const int h = (blockIdx.x >> 6) & (NH - 1);
    const int b = blockIdx.x >> 10;
    const int row0 = b * LSEQ + n * 64;
    const unsigned chb = (unsigned)blockIdx.x * CHW;
    const int i15 = l & 15;
    const int p = w * 16 + i15;

    bf16x8 aX[2], aH[2];
    #pragma unroll
    for (int kk = 0; kk < 2; ++kk) {
        const int c0 = kk * 32 + ((l >> 4) << 3);
        bf16x8 x;
        #pragma unroll
        for (int e = 0; e < 8; ++e)
            x[e] = (__bf16)Xg[((unsigned)(row0 + c0 + e) * NH + h) * 64 + p];
        aX[kk] = x;
        FragU f; f.u = *(const uint4*)&hws[chb + (((kk * 4 + w) * 64 + l) << 3)];
        aH[kk] = f.b;
    }

    const f32x4 zero = {0.f, 0.f, 0.f, 0.f};
    f32x4 accY[4] = {zero, zero, zero, zero};
    f32x4 accI[4] = {zero, zero, zero, zero};
    #pragma unroll
    for (int kk = 0; kk < 2; ++kk) {
        const int j0 = kk * 32 + ((l >> 4) << 3);
        const int wj = j0 >> 4;
        const int q = (j0 >> 2) & 3;
        #pragma unroll
        for (int ti = 0; ti < 4; ++ti) {
            FragU mf, cf;
            *(ushort4*)&mf.s[0] = *(const ushort4*)&Mws[chb + (((ti * 4 + wj) * 64 + q * 16 + i15) << 2)];
            *(ushort4*)&mf.s[4] = *(const ushort4*)&Mws[chb + (((ti * 4 + wj) * 64 + (q + 1) * 16 + i15) << 2)];
            cf.u = *(const uint4*)&Csws[chb + (((kk * 4 + ti) * 64 + l) << 3)];
            accY[ti] = __builtin_amdgcn_mfma_f32_16x16x32_bf16(aX[kk], mf.b, accY[ti], 0, 0, 0);
            accI[ti] = __builtin_amdgcn_mfma_f32_16x16x32_bf16(aH[kk], cf.b, accI[ti], 0, 0, 0);
        }
    }

    const int pbase = w * 16 + ((l >> 4) << 2);
    #pragma unroll
    for (int ti = 0; ti < 4; ++ti) {
        const int i = ti * 16 + i15;
        float4 o;
        o.x = accY[ti][0] + accI[ti][0];
        o.y = accY[ti][1] + accI[ti][1];
        o.z = accY[ti][2] + accI[ti][2];
        o.w = accY[ti][3] + accI[ti][3];
        *(float4*)&Yg[((unsigned)(row0 + i) * NH + h) * 64 + pbase] = o;
    }
}

extern "C" void kernel_launch(void* const* d_in, const int* in_sizes, int n_in,
                              void* d_out, int out_size, void* d_ws, size_t ws_size,
                              hipStream_t stream) {
    const float* X = (const float*)d_in[0];
    const float* A = (const float*)d_in[1];
    const float* Bm = (const float*)d_in[2];
    const float* Cm = (const float*)d_in[3];
    float* Y = (float*)d_out;
    unsigned short* hws = (unsigned short*)d_ws;        // 16.8 MB
    unsigned short* Mws = hws + TILE_USHORTS;           // 16.8 MB
    unsigned short* Csws = Mws + TILE_USHORTS;          // 16.8 MB
    float* dws = (float*)(Csws + TILE_USHORTS);         // 8 KB (log chunk decays)

    ssd_k1<<<NCH, 256, 0, stream>>>(X, A, Bm, Cm, hws, Mws, Csws, dws);
    ssd_scan<<<BSZ * NH * SCAN_G, 256, 0, stream>>>(hws, dws);
    ssd_k3<<<NCH, 256, 0, stream>>>(X, Mws, Csws, hws, Y);
}